// Round 1
// baseline (600.989 us; speedup 1.0000x reference)
//
#include <hip/hip_runtime.h>
#include <cstdint>
#include <cstddef>

// ---------------------------------------------------------------------------
// MultiHeadAttention (linear attention + relative position bias, no softmax)
// B=4 S=1024 E=1024 H=16 D=64.  All-bf16 MFMA pipeline:
//   1. kconv_T      : W_qkv, W_out  fp32 -> bf16, transposed to (N,K)
//   2. kgemm_qkv    : qkv = x@Wqkv + b  (128x128 tile MFMA), scatter to q/k/v (bh,s,d) bf16
//   3. ktrans_v     : v (bh,s,d) -> vt (bh,d,s)
//   4. kpq          : Pq[bh][x][y] = sum_c pe[x,y,c]*q[bh,x,c]   (per-x MFMA, pe read once)
//   5. kattn        : O = ((QK^T + Pq)*scale) @ V, fused, 128-query tiles
//   6. kgemm_out    : out = attn@Wout + b (fp32 out)
// ---------------------------------------------------------------------------

typedef unsigned short u16;
typedef __bf16 bf16x8 __attribute__((ext_vector_type(8)));
typedef float  f32x4  __attribute__((ext_vector_type(4)));
typedef unsigned short u16x8 __attribute__((ext_vector_type(8)));

#define MFMA16(a, b, c) __builtin_amdgcn_mfma_f32_16x16x32_bf16((a), (b), (c), 0, 0, 0)

__device__ __forceinline__ u16 f2bf(float f) {
    __bf16 h = (__bf16)f;                     // RNE convert
    return __builtin_bit_cast(u16, h);
}
__device__ __forceinline__ float bf2f(u16 u) {
    unsigned int x = ((unsigned int)u) << 16;
    return __builtin_bit_cast(float, x);
}
__device__ __forceinline__ u16x8 pack8(float4 a, float4 b) {
    u16x8 v;
    v[0] = f2bf(a.x); v[1] = f2bf(a.y); v[2] = f2bf(a.z); v[3] = f2bf(a.w);
    v[4] = f2bf(b.x); v[5] = f2bf(b.y); v[6] = f2bf(b.z); v[7] = f2bf(b.w);
    return v;
}

// --------------------------------------------------------------------------
// Transpose+convert: in (R rows x C cols) fp32 -> out (C rows x R cols) bf16
// grid (C/64, R/64), block 256
// --------------------------------------------------------------------------
__global__ __launch_bounds__(256) void kconv_T(const float* __restrict__ in,
                                               u16* __restrict__ out, int R, int C) {
    __shared__ float tile[64][68];            // 68: float4-aligned (272B), bank spread
    const int t  = threadIdx.x;
    const int r0 = blockIdx.y * 64, c0 = blockIdx.x * 64;
    const int rr = t >> 4, c4 = t & 15;
    for (int p = 0; p < 4; ++p) {
        int r = rr + p * 16;
        float4 v = *(const float4*)&in[(size_t)(r0 + r) * C + c0 + c4 * 4];
        *(float4*)&tile[r][c4 * 4] = v;
    }
    __syncthreads();
    for (int p = 0; p < 4; ++p) {
        int n = rr + p * 16;
        ushort4 o;
        o.x = f2bf(tile[c4 * 4 + 0][n]);
        o.y = f2bf(tile[c4 * 4 + 1][n]);
        o.z = f2bf(tile[c4 * 4 + 2][n]);
        o.w = f2bf(tile[c4 * 4 + 3][n]);
        *(ushort4*)&out[(size_t)(c0 + n) * R + r0 + c4 * 4] = o;
    }
}

// --------------------------------------------------------------------------
// QKV GEMM: C(4096x3072) = X(4096x1024 fp32) @ WT(3072x1024 bf16)^T + bias
// 128x128 tile, 4 waves (2x2 of 64x64), 4x4 16x16x32 MFMA per wave.
// Epilogue scatters bf16 into q/k/v buffers laid out (bh=b*16+h, s, d).
// grid (24, 32), block 256
// --------------------------------------------------------------------------
__global__ __launch_bounds__(256, 3) void kgemm_qkv(const float* __restrict__ X,
                                                    const u16* __restrict__ WT,
                                                    const float* __restrict__ bias,
                                                    u16* __restrict__ qb,
                                                    u16* __restrict__ kb,
                                                    u16* __restrict__ vb) {
    __shared__ u16 a_s[128 * 72];
    __shared__ u16 b_s[128 * 72];
    const int t = threadIdx.x;
    const int m0 = blockIdx.y * 128, n0 = blockIdx.x * 128;
    const int lane = t & 63, w = t >> 6, lm = lane & 15, lq = lane >> 4;
    const int mb = (w >> 1) * 64, nb = (w & 1) * 64;
    const int srow = t >> 3, scc = t & 7;

    f32x4 acc[4][4] = {};
    for (int k0 = 0; k0 < 1024; k0 += 64) {
        __syncthreads();
        for (int p = 0; p < 4; ++p) {
            int r = srow + p * 32;
            const float* src = &X[(size_t)(m0 + r) * 1024 + k0 + scc * 8];
            float4 f0 = *(const float4*)&src[0];
            float4 f1 = *(const float4*)&src[4];
            *(u16x8*)&a_s[r * 72 + scc * 8] = pack8(f0, f1);
        }
        for (int p = 0; p < 4; ++p) {
            int r = srow + p * 32;
            *(u16x8*)&b_s[r * 72 + scc * 8] =
                *(const u16x8*)&WT[(size_t)(n0 + r) * 1024 + k0 + scc * 8];
        }
        __syncthreads();
#pragma unroll
        for (int ks = 0; ks < 2; ++ks) {
            bf16x8 af[4], bfr[4];
#pragma unroll
            for (int mt = 0; mt < 4; ++mt)
                af[mt] = *(const bf16x8*)&a_s[(mb + mt * 16 + lm) * 72 + ks * 32 + lq * 8];
#pragma unroll
            for (int nt = 0; nt < 4; ++nt)
                bfr[nt] = *(const bf16x8*)&b_s[(nb + nt * 16 + lm) * 72 + ks * 32 + lq * 8];
#pragma unroll
            for (int mt = 0; mt < 4; ++mt)
#pragma unroll
                for (int nt = 0; nt < 4; ++nt)
                    acc[mt][nt] = MFMA16(af[mt], bfr[nt], acc[mt][nt]);
        }
    }
    // epilogue: +bias, bf16, scatter to q/k/v (bh, s, d)
    for (int nt = 0; nt < 4; ++nt) {
        int col = n0 + nb + nt * 16 + lm;
        float bv = bias[col];
        int which = col >> 10;
        int h = (col >> 6) & 15, d = col & 63;
        u16* dst = (which == 0) ? qb : ((which == 1) ? kb : vb);
        for (int mt = 0; mt < 4; ++mt) {
            for (int i = 0; i < 4; ++i) {
                int row = m0 + mb + mt * 16 + lq * 4 + i;
                int b = row >> 10, s = row & 1023;
                dst[((size_t)((b * 16 + h) * 1024 + s)) * 64 + d] =
                    f2bf(acc[mt][nt][i] + bv);
            }
        }
    }
}

// --------------------------------------------------------------------------
// V transpose: v (bh, s, d) -> vt (bh, d, s).  grid 64*16, block 256
// --------------------------------------------------------------------------
__global__ __launch_bounds__(256) void ktrans_v(const u16* __restrict__ v,
                                                u16* __restrict__ vt) {
    __shared__ u16 tv[64 * 72];
    const int bid = blockIdx.x;
    const int bh = bid >> 4, st = bid & 15;
    const int s0 = st * 64;
    const int t = threadIdx.x;
    const int rr = t >> 3, cc = t & 7;
    for (int p = 0; p < 2; ++p) {
        int s = rr + p * 32;
        *(u16x8*)&tv[s * 72 + cc * 8] =
            *(const u16x8*)&v[(size_t)(bh * 1024 + s0 + s) * 64 + cc * 8];
    }
    __syncthreads();
    for (int p = 0; p < 2; ++p) {
        int d = rr + p * 32;
        u16x8 o;
#pragma unroll
        for (int j = 0; j < 8; ++j) o[j] = tv[(cc * 8 + j) * 72 + d];
        *(u16x8*)&vt[(size_t)(bh * 64 + d) * 1024 + s0 + cc * 8] = o;
    }
}

// --------------------------------------------------------------------------
// Pq[bh][x][y] = sum_c pe[x,y,c] * q[bh,x,c]   (raw, scale applied in kattn)
// One block per x.  q_x for all 64 bh staged once; pe streamed (read once
// device-wide).  Per 64-y chunk: MFMA (A=pe chunk, B=q), D(y,bh) -> LDS ->
// coalesced bf16 store.  grid 1024, block 256
// --------------------------------------------------------------------------
__global__ __launch_bounds__(256, 2) void kpq(const u16* __restrict__ qb,
                                              const float* __restrict__ pe,
                                              u16* __restrict__ Pq) {
    __shared__ u16 q_s[64 * 72];
    __shared__ u16 pe_s[64 * 72];
    __shared__ u16 o_s[64 * 72];
    const int x = blockIdx.x;
    const int t = threadIdx.x;
    const int lane = t & 63, w = t >> 6, lm = lane & 15, lq = lane >> 4;
    {   // stage q_x: 64 bh x 64 c
        int rr = t >> 3, cc = t & 7;
        for (int p = 0; p < 2; ++p) {
            int bh = rr + p * 32;
            *(u16x8*)&q_s[bh * 72 + cc * 8] =
                *(const u16x8*)&qb[(size_t)(bh * 1024 + x) * 64 + cc * 8];
        }
    }
    const int yl = t >> 2, cq = t & 3;
    for (int y0 = 0; y0 < 1024; y0 += 64) {
        __syncthreads();
        {   // stage pe[x, y0+yl, :] -> bf16
            const float* src = &pe[(size_t)x * 65536 + (size_t)(y0 + yl) * 64 + cq * 16];
            float4 f0 = *(const float4*)&src[0];
            float4 f1 = *(const float4*)&src[4];
            float4 f2 = *(const float4*)&src[8];
            float4 f3 = *(const float4*)&src[12];
            *(u16x8*)&pe_s[yl * 72 + cq * 16]     = pack8(f0, f1);
            *(u16x8*)&pe_s[yl * 72 + cq * 16 + 8] = pack8(f2, f3);
        }
        __syncthreads();
        // D[y][bh] = sum_c pe[y][c] * q[bh][c]; wave w owns y-strip [16w,16w+16)
        f32x4 acc[4] = {};
#pragma unroll
        for (int ks = 0; ks < 2; ++ks) {
            bf16x8 a = *(const bf16x8*)&pe_s[(16 * w + lm) * 72 + ks * 32 + lq * 8];
#pragma unroll
            for (int nt = 0; nt < 4; ++nt) {
                bf16x8 b = *(const bf16x8*)&q_s[(nt * 16 + lm) * 72 + ks * 32 + lq * 8];
                acc[nt] = MFMA16(a, b, acc[nt]);
            }
        }
#pragma unroll
        for (int nt = 0; nt < 4; ++nt) {
            ushort4 o;
            o.x = f2bf(acc[nt][0]); o.y = f2bf(acc[nt][1]);
            o.z = f2bf(acc[nt][2]); o.w = f2bf(acc[nt][3]);
            *(ushort4*)&o_s[(nt * 16 + lm) * 72 + 16 * w + lq * 4] = o;
        }
        __syncthreads();
        {   // coalesced out: thread -> (bh = t/4, 16 y's)
            int bh = t >> 2, yc = t & 3;
            u16x8 r0 = *(const u16x8*)&o_s[bh * 72 + yc * 16];
            u16x8 r1 = *(const u16x8*)&o_s[bh * 72 + yc * 16 + 8];
            size_t base = ((size_t)bh * 1024 + x) * 1024 + y0 + yc * 16;
            *(u16x8*)&Pq[base]     = r0;
            *(u16x8*)&Pq[base + 8] = r1;
        }
    }
}

// --------------------------------------------------------------------------
// Fused attention: O[x,d] = sum_y (q_x.k_y + Pq[x,y])*scale * v[y,d]
// Block = (bh, 128-query tile), 4 waves; y-loop in 64-key tiles.
// QK^T computed transposed (A=K, B=Q) so S writes to LDS are ds_write_b64;
// Pq tile pre-staged into s_s and consumed in-place (wave-private regions).
// grid 512, block 256
// --------------------------------------------------------------------------
__global__ __launch_bounds__(256, 2) void kattn(const u16* __restrict__ qb,
                                                const u16* __restrict__ kb,
                                                const u16* __restrict__ vt,
                                                const u16* __restrict__ Pq,
                                                u16* __restrict__ attnb) {
    __shared__ u16 q_s[128 * 72];
    __shared__ u16 k_s[64 * 72];
    __shared__ u16 v_s[64 * 72];   // vt tile: rows d, cols y
    __shared__ u16 s_s[128 * 72];  // doubles as Pq tile then S tile (x rows, y cols)
    const int bid = blockIdx.x;
    const int bh = bid >> 3, xt = bid & 7;
    const int x0 = xt * 128;
    const int t = threadIdx.x;
    const int lane = t & 63, w = t >> 6, lm = lane & 15, lq = lane >> 4;
    const int rr = t >> 3, cc = t & 7;

    for (int p = 0; p < 4; ++p) {
        int r = rr + p * 32;
        *(u16x8*)&q_s[r * 72 + cc * 8] =
            *(const u16x8*)&qb[(size_t)(bh * 1024 + x0 + r) * 64 + cc * 8];
    }
    f32x4 oacc[2][4] = {};
    for (int y0 = 0; y0 < 1024; y0 += 64) {
        __syncthreads();
        for (int p = 0; p < 2; ++p) {
            int r = rr + p * 32;
            *(u16x8*)&k_s[r * 72 + cc * 8] =
                *(const u16x8*)&kb[(size_t)(bh * 1024 + y0 + r) * 64 + cc * 8];
            *(u16x8*)&v_s[r * 72 + cc * 8] =
                *(const u16x8*)&vt[(size_t)(bh * 64 + r) * 1024 + y0 + cc * 8];
        }
        for (int p = 0; p < 4; ++p) {
            int r = rr + p * 32;
            *(u16x8*)&s_s[r * 72 + cc * 8] =
                *(const u16x8*)&Pq[((size_t)(bh * 1024 + x0 + r)) * 1024 + y0 + cc * 8];
        }
        __syncthreads();
        // S^T = K.Q^T : D[y][x]; wave w owns x-strip [32w, 32w+32)
        f32x4 sacc[4][2] = {};
#pragma unroll
        for (int ks = 0; ks < 2; ++ks) {
            bf16x8 bq[2];
#pragma unroll
            for (int nt = 0; nt < 2; ++nt)
                bq[nt] = *(const bf16x8*)&q_s[(32 * w + nt * 16 + lm) * 72 + ks * 32 + lq * 8];
#pragma unroll
            for (int mt = 0; mt < 4; ++mt) {
                bf16x8 ak = *(const bf16x8*)&k_s[(mt * 16 + lm) * 72 + ks * 32 + lq * 8];
#pragma unroll
                for (int nt = 0; nt < 2; ++nt)
                    sacc[mt][nt] = MFMA16(ak, bq[nt], sacc[mt][nt]);
            }
        }
        // s = (qk + pq) * scale -> bf16, in-place into s_s (lane-private addrs)
#pragma unroll
        for (int nt = 0; nt < 2; ++nt) {
            int xl = 32 * w + nt * 16 + lm;
#pragma unroll
            for (int mt = 0; mt < 4; ++mt) {
                int yl = mt * 16 + lq * 4;
                ushort4 pq = *(const ushort4*)&s_s[xl * 72 + yl];
                ushort4 o;
                o.x = f2bf((sacc[mt][nt][0] + bf2f(pq.x)) * 0.125f);
                o.y = f2bf((sacc[mt][nt][1] + bf2f(pq.y)) * 0.125f);
                o.z = f2bf((sacc[mt][nt][2] + bf2f(pq.z)) * 0.125f);
                o.w = f2bf((sacc[mt][nt][3] + bf2f(pq.w)) * 0.125f);
                *(ushort4*)&s_s[xl * 72 + yl] = o;
            }
        }
        // O += S.V : A = s_s (x rows), B = v_s (d rows) — wave-private strip
#pragma unroll
        for (int ks = 0; ks < 2; ++ks) {
            bf16x8 as[2];
#pragma unroll
            for (int mt = 0; mt < 2; ++mt)
                as[mt] = *(const bf16x8*)&s_s[(32 * w + mt * 16 + lm) * 72 + ks * 32 + lq * 8];
#pragma unroll
            for (int nt = 0; nt < 4; ++nt) {
                bf16x8 bv = *(const bf16x8*)&v_s[(nt * 16 + lm) * 72 + ks * 32 + lq * 8];
#pragma unroll
                for (int mt = 0; mt < 2; ++mt)
                    oacc[mt][nt] = MFMA16(as[mt], bv, oacc[mt][nt]);
            }
        }
    }
    // write attn (B, S, E=h*64+d) bf16
    const int b = bh >> 4, h = bh & 15;
    for (int mt = 0; mt < 2; ++mt) {
        for (int nt = 0; nt < 4; ++nt) {
            int d = nt * 16 + lm;
            for (int i = 0; i < 4; ++i) {
                int s = x0 + 32 * w + mt * 16 + lq * 4 + i;
                attnb[((size_t)(b * 1024 + s)) * 1024 + h * 64 + d] = f2bf(oacc[mt][nt][i]);
            }
        }
    }
}

// --------------------------------------------------------------------------
// Out projection: out(4096x1024 fp32) = attn(bf16) @ WoutT^T + b_out
// grid (8, 32), block 256
// --------------------------------------------------------------------------
__global__ __launch_bounds__(256, 3) void kgemm_out(const u16* __restrict__ A,
                                                    const u16* __restrict__ WT,
                                                    const float* __restrict__ bias,
                                                    float* __restrict__ out) {
    __shared__ u16 a_s[128 * 72];
    __shared__ u16 b_s[128 * 72];
    const int t = threadIdx.x;
    const int m0 = blockIdx.y * 128, n0 = blockIdx.x * 128;
    const int lane = t & 63, w = t >> 6, lm = lane & 15, lq = lane >> 4;
    const int mb = (w >> 1) * 64, nb = (w & 1) * 64;
    const int srow = t >> 3, scc = t & 7;

    f32x4 acc[4][4] = {};
    for (int k0 = 0; k0 < 1024; k0 += 64) {
        __syncthreads();
        for (int p = 0; p < 4; ++p) {
            int r = srow + p * 32;
            *(u16x8*)&a_s[r * 72 + scc * 8] =
                *(const u16x8*)&A[(size_t)(m0 + r) * 1024 + k0 + scc * 8];
        }
        for (int p = 0; p < 4; ++p) {
            int r = srow + p * 32;
            *(u16x8*)&b_s[r * 72 + scc * 8] =
                *(const u16x8*)&WT[(size_t)(n0 + r) * 1024 + k0 + scc * 8];
        }
        __syncthreads();
#pragma unroll
        for (int ks = 0; ks < 2; ++ks) {
            bf16x8 af[4], bfr[4];
#pragma unroll
            for (int mt = 0; mt < 4; ++mt)
                af[mt] = *(const bf16x8*)&a_s[(mb + mt * 16 + lm) * 72 + ks * 32 + lq * 8];
#pragma unroll
            for (int nt = 0; nt < 4; ++nt)
                bfr[nt] = *(const bf16x8*)&b_s[(nb + nt * 16 + lm) * 72 + ks * 32 + lq * 8];
#pragma unroll
            for (int mt = 0; mt < 4; ++mt)
#pragma unroll
                for (int nt = 0; nt < 4; ++nt)
                    acc[mt][nt] = MFMA16(af[mt], bfr[nt], acc[mt][nt]);
        }
    }
    for (int nt = 0; nt < 4; ++nt) {
        int col = n0 + nb + nt * 16 + lm;
        float bv = bias[col];
        for (int mt = 0; mt < 4; ++mt) {
            for (int i = 0; i < 4; ++i) {
                int row = m0 + mb + mt * 16 + lq * 4 + i;
                out[(size_t)row * 1024 + col] = acc[mt][nt][i] + bv;
            }
        }
    }
}

// --------------------------------------------------------------------------
extern "C" void kernel_launch(void* const* d_in, const int* in_sizes, int n_in,
                              void* d_out, int out_size, void* d_ws, size_t ws_size,
                              hipStream_t stream) {
    (void)in_sizes; (void)n_in; (void)out_size; (void)ws_size;
    const float* x    = (const float*)d_in[0];
    const float* Wqkv = (const float*)d_in[1];
    const float* bqkv = (const float*)d_in[2];
    const float* pe   = (const float*)d_in[3];
    const float* Wout = (const float*)d_in[4];
    const float* bout = (const float*)d_in[5];
    float* out = (float*)d_out;

    char* ws = (char*)d_ws;
    u16* wqkvT = (u16*)ws;  ws += (size_t)3072 * 1024 * 2;   // 6 MB
    u16* woutT = (u16*)ws;  ws += (size_t)1024 * 1024 * 2;   // 2 MB
    u16* qb    = (u16*)ws;  ws += (size_t)64 * 1024 * 64 * 2; // 8 MB
    u16* kb    = (u16*)ws;  ws += (size_t)64 * 1024 * 64 * 2; // 8 MB
    u16* vb    = (u16*)ws;  ws += (size_t)64 * 1024 * 64 * 2; // 8 MB
    u16* vtb   = (u16*)ws;  ws += (size_t)64 * 64 * 1024 * 2; // 8 MB
    u16* attnb = (u16*)ws;  ws += (size_t)4 * 1024 * 1024 * 2; // 8 MB
    u16* pq    = (u16*)ws;  ws += (size_t)64 * 1024 * 1024 * 2; // 128 MB

    kconv_T<<<dim3(48, 16), 256, 0, stream>>>(Wqkv, wqkvT, 1024, 3072);
    kconv_T<<<dim3(16, 16), 256, 0, stream>>>(Wout, woutT, 1024, 1024);
    kgemm_qkv<<<dim3(24, 32), 256, 0, stream>>>(x, wqkvT, bqkv, qb, kb, vb);
    ktrans_v<<<1024, 256, 0, stream>>>(vb, vtb);
    kpq<<<1024, 256, 0, stream>>>(qb, pe, pq);
    kattn<<<512, 256, 0, stream>>>(qb, kb, vtb, pq, attnb);
    kgemm_out<<<dim3(8, 32), 256, 0, stream>>>(attnb, woutT, bout, out);
}

// Round 2
// 543.325 us; speedup vs baseline: 1.1061x; 1.1061x over previous
//
#include <hip/hip_runtime.h>
#include <cstdint>
#include <cstddef>

// ---------------------------------------------------------------------------
// MultiHeadAttention (linear attention + relative position bias, no softmax)
// B=4 S=1024 E=1024 H=16 D=64.  All-bf16 MFMA pipeline, m97-style staging:
//   1. kxconv       : x fp32 -> bf16
//   2. kconv_T      : W_qkv, W_out  fp32 -> bf16, transposed to (N,K)
//   3. kgemm_qkv    : qkv = x@Wqkv + b  (128x128 tile, global_load_lds), scatter q/k/v
//   4. ktrans_v     : v (bh,s,d) -> vt (bh,d,s)
//   5. kpq          : Pq[bh][x][y] = sum_c pe[x,y,c]*q[bh,x,c]  (double-buffered pe)
//   6. kattn        : O = ((QK^T + Pq)*scale) @ V  (Pq read direct in C-layout)
//   7. kgemm_out    : out = attn@Wout + b (fp32 out)
// ---------------------------------------------------------------------------

typedef unsigned short u16;
typedef __bf16 bf16x8 __attribute__((ext_vector_type(8)));
typedef float  f32x4  __attribute__((ext_vector_type(4)));
typedef unsigned short u16x8 __attribute__((ext_vector_type(8)));

#define MFMA16(a, b, c) __builtin_amdgcn_mfma_f32_16x16x32_bf16((a), (b), (c), 0, 0, 0)

// async global->LDS, 16 B per lane; LDS dest = wave-uniform base + lane*16
#define GLOAD16(g, l)                                                        \
    __builtin_amdgcn_global_load_lds(                                        \
        (const __attribute__((address_space(1))) unsigned int*)(g),          \
        (__attribute__((address_space(3))) unsigned int*)(l), 16, 0, 0)

__device__ __forceinline__ u16 f2bf(float f) {
    __bf16 h = (__bf16)f;                     // RNE convert
    return __builtin_bit_cast(u16, h);
}
__device__ __forceinline__ float bf2f(u16 u) {
    unsigned int x = ((unsigned int)u) << 16;
    return __builtin_bit_cast(float, x);
}
__device__ __forceinline__ u16x8 pack8(float4 a, float4 b) {
    u16x8 v;
    v[0] = f2bf(a.x); v[1] = f2bf(a.y); v[2] = f2bf(a.z); v[3] = f2bf(a.w);
    v[4] = f2bf(b.x); v[5] = f2bf(b.y); v[6] = f2bf(b.z); v[7] = f2bf(b.w);
    return v;
}

// --------------------------------------------------------------------------
// x fp32 -> bf16, 8 elems/thread.  grid 2048, block 256
// --------------------------------------------------------------------------
__global__ __launch_bounds__(256) void kxconv(const float* __restrict__ in,
                                              u16* __restrict__ out) {
    int i = (blockIdx.x * 256 + threadIdx.x) * 8;
    float4 f0 = *(const float4*)&in[i];
    float4 f1 = *(const float4*)&in[i + 4];
    *(u16x8*)&out[i] = pack8(f0, f1);
}

// --------------------------------------------------------------------------
// Transpose+convert: in (R x C) fp32 -> out (C x R) bf16.  grid (C/64, R/64)
// --------------------------------------------------------------------------
__global__ __launch_bounds__(256) void kconv_T(const float* __restrict__ in,
                                               u16* __restrict__ out, int R, int C) {
    __shared__ float tile[64][68];
    const int t  = threadIdx.x;
    const int r0 = blockIdx.y * 64, c0 = blockIdx.x * 64;
    const int rr = t >> 4, c4 = t & 15;
    for (int p = 0; p < 4; ++p) {
        int r = rr + p * 16;
        float4 v = *(const float4*)&in[(size_t)(r0 + r) * C + c0 + c4 * 4];
        *(float4*)&tile[r][c4 * 4] = v;
    }
    __syncthreads();
    for (int p = 0; p < 4; ++p) {
        int n = rr + p * 16;
        ushort4 o;
        o.x = f2bf(tile[c4 * 4 + 0][n]);
        o.y = f2bf(tile[c4 * 4 + 1][n]);
        o.z = f2bf(tile[c4 * 4 + 2][n]);
        o.w = f2bf(tile[c4 * 4 + 3][n]);
        *(ushort4*)&out[(size_t)(c0 + n) * R + r0 + c4 * 4] = o;
    }
}

// --------------------------------------------------------------------------
// QKV GEMM (m97-style): C(4096x3072) = Xb(bf16) @ WT(3072x1024)^T + bias
// 128x128 tile, BK=64, unpadded LDS, global_load_lds width 16.
// Epilogue scatters bf16 into q/k/v (bh, s, d).  grid (24,32), block 256
// --------------------------------------------------------------------------
__global__ __launch_bounds__(256, 2) void kgemm_qkv(const u16* __restrict__ A,
                                                    const u16* __restrict__ WT,
                                                    const float* __restrict__ bias,
                                                    u16* __restrict__ qb,
                                                    u16* __restrict__ kb,
                                                    u16* __restrict__ vb) {
    __shared__ u16 a_s[128 * 64];
    __shared__ u16 b_s[128 * 64];
    const int t = threadIdx.x;
    const int m0 = blockIdx.y * 128, n0 = blockIdx.x * 128;
    const int lane = t & 63, w = t >> 6, lm = lane & 15, lq = lane >> 4;
    const int mb = (w >> 1) * 64, nb = (w & 1) * 64;
    const int sr = t >> 3, sc = (t & 7) * 8;

    f32x4 acc[4][4] = {};
    for (int k0 = 0; k0 < 1024; k0 += 64) {
        __syncthreads();
#pragma unroll
        for (int p = 0; p < 4; ++p) {
            GLOAD16(&A [(size_t)(m0 + p * 32 + sr) * 1024 + k0 + sc], &a_s[p * 2048 + t * 8]);
            GLOAD16(&WT[(size_t)(n0 + p * 32 + sr) * 1024 + k0 + sc], &b_s[p * 2048 + t * 8]);
        }
        __syncthreads();
#pragma unroll
        for (int ks = 0; ks < 2; ++ks) {
            bf16x8 af[4], bfr[4];
#pragma unroll
            for (int mt = 0; mt < 4; ++mt)
                af[mt] = *(const bf16x8*)&a_s[(mb + mt * 16 + lm) * 64 + ks * 32 + lq * 8];
#pragma unroll
            for (int nt = 0; nt < 4; ++nt)
                bfr[nt] = *(const bf16x8*)&b_s[(nb + nt * 16 + lm) * 64 + ks * 32 + lq * 8];
#pragma unroll
            for (int mt = 0; mt < 4; ++mt)
#pragma unroll
                for (int nt = 0; nt < 4; ++nt)
                    acc[mt][nt] = MFMA16(af[mt], bfr[nt], acc[mt][nt]);
        }
    }
    for (int nt = 0; nt < 4; ++nt) {
        int col = n0 + nb + nt * 16 + lm;
        float bv = bias[col];
        int which = col >> 10;
        int h = (col >> 6) & 15, d = col & 63;
        u16* dst = (which == 0) ? qb : ((which == 1) ? kb : vb);
        for (int mt = 0; mt < 4; ++mt) {
            for (int i = 0; i < 4; ++i) {
                int row = m0 + mb + mt * 16 + lq * 4 + i;
                int b = row >> 10, s = row & 1023;
                dst[((size_t)((b * 16 + h) * 1024 + s)) * 64 + d] =
                    f2bf(acc[mt][nt][i] + bv);
            }
        }
    }
}

// --------------------------------------------------------------------------
// V transpose: v (bh, s, d) -> vt (bh, d, s).  grid 1024, block 256
// --------------------------------------------------------------------------
__global__ __launch_bounds__(256) void ktrans_v(const u16* __restrict__ v,
                                                u16* __restrict__ vt) {
    __shared__ u16 tv[64 * 72];
    const int bid = blockIdx.x;
    const int bh = bid >> 4, s0 = (bid & 15) * 64;
    const int t = threadIdx.x;
    const int rr = t >> 3, cc = t & 7;
    for (int p = 0; p < 2; ++p) {
        int s = rr + p * 32;
        *(u16x8*)&tv[s * 72 + cc * 8] =
            *(const u16x8*)&v[(size_t)(bh * 1024 + s0 + s) * 64 + cc * 8];
    }
    __syncthreads();
    for (int p = 0; p < 2; ++p) {
        int d = rr + p * 32;
        u16x8 o;
#pragma unroll
        for (int j = 0; j < 8; ++j) o[j] = tv[(cc * 8 + j) * 72 + d];
        *(u16x8*)&vt[(size_t)(bh * 64 + d) * 1024 + s0 + cc * 8] = o;
    }
}

// --------------------------------------------------------------------------
// Pq[bh][x][y] = sum_c pe[x,y,c] * q[bh,x,c]  (scale applied in kattn)
// One block per x; pe streamed once device-wide; double-buffered pe_s/o_s
// with register prefetch — 2 barriers/iter, HBM latency hidden under MFMA.
// grid 1024, block 256
// --------------------------------------------------------------------------
__global__ __launch_bounds__(256, 2) void kpq(const u16* __restrict__ qb,
                                              const float* __restrict__ pe,
                                              u16* __restrict__ Pq) {
    __shared__ u16 q_s[64 * 64];        // global_load_lds, stride 64
    __shared__ u16 pe_s[2][64 * 80];
    __shared__ u16 o_s[2][64 * 72];
    const int x = blockIdx.x;
    const int t = threadIdx.x;
    const int lane = t & 63, w = t >> 6, lm = lane & 15, lq = lane >> 4;
    // stage q_x: 64 bh x 64 c  (per-lane gather, 16 B each)
#pragma unroll
    for (int p = 0; p < 2; ++p)
        GLOAD16(&qb[(size_t)((p * 32 + (t >> 3)) * 1024 + x) * 64 + (t & 7) * 8],
                &q_s[p * 2048 + t * 8]);
    const int yl = t >> 2, cq = (t & 3) * 16;
    const float* pex = pe + (size_t)x * 65536;
    float4 r0, r1, r2, r3;
    {
        const float* src = &pex[(size_t)yl * 64 + cq];
        r0 = *(const float4*)&src[0];  r1 = *(const float4*)&src[4];
        r2 = *(const float4*)&src[8];  r3 = *(const float4*)&src[12];
    }
    int cur = 0;
    const int obh = t >> 2, oyc = t & 3;
    for (int it = 0; it < 16; ++it) {
        // regs (chunk it) -> pe_s[cur]
        *(u16x8*)&pe_s[cur][yl * 80 + cq]     = pack8(r0, r1);
        *(u16x8*)&pe_s[cur][yl * 80 + cq + 8] = pack8(r2, r3);
        __syncthreads();                       // pe_s ready (covers q_s on it=0)
        if (it < 15) {                         // prefetch chunk it+1
            const float* src = &pex[(size_t)((it + 1) * 64 + yl) * 64 + cq];
            r0 = *(const float4*)&src[0];  r1 = *(const float4*)&src[4];
            r2 = *(const float4*)&src[8];  r3 = *(const float4*)&src[12];
        }
        // D[y][bh]: wave w owns y-strip [16w, 16w+16)
        f32x4 acc[4] = {};
#pragma unroll
        for (int ks = 0; ks < 2; ++ks) {
            bf16x8 a = *(const bf16x8*)&pe_s[cur][(16 * w + lm) * 80 + ks * 32 + lq * 8];
#pragma unroll
            for (int nt = 0; nt < 4; ++nt) {
                bf16x8 b = *(const bf16x8*)&q_s[(nt * 16 + lm) * 64 + ks * 32 + lq * 8];
                acc[nt] = MFMA16(a, b, acc[nt]);
            }
        }
#pragma unroll
        for (int nt = 0; nt < 4; ++nt) {
            ushort4 o;
            o.x = f2bf(acc[nt][0]); o.y = f2bf(acc[nt][1]);
            o.z = f2bf(acc[nt][2]); o.w = f2bf(acc[nt][3]);
            *(ushort4*)&o_s[cur][(nt * 16 + lm) * 72 + 16 * w + lq * 4] = o;
        }
        __syncthreads();                       // o_s ready
        {   // coalesced store: thread -> (bh, 16 y's)
            u16x8 a0 = *(const u16x8*)&o_s[cur][obh * 72 + oyc * 16];
            u16x8 a1 = *(const u16x8*)&o_s[cur][obh * 72 + oyc * 16 + 8];
            size_t base = ((size_t)obh * 1024 + x) * 1024 + it * 64 + oyc * 16;
            *(u16x8*)&Pq[base]     = a0;
            *(u16x8*)&Pq[base + 8] = a1;
        }
        cur ^= 1;
    }
}

// --------------------------------------------------------------------------
// Fused attention: O[x,d] = sum_y (q_x.k_y + Pq[x,y])*scale * v[y,d]
// Block = (bh, 128-query tile); y-loop 64-key tiles; q/k/vt via
// global_load_lds; Pq fragments read DIRECT from global in MFMA C-layout.
// S round-trips s_s (wave-private strips -> no extra barrier).
// grid 512, block 256
// --------------------------------------------------------------------------
__global__ __launch_bounds__(256, 2) void kattn(const u16* __restrict__ qb,
                                                const u16* __restrict__ kb,
                                                const u16* __restrict__ vt,
                                                const u16* __restrict__ Pq,
                                                u16* __restrict__ attnb) {
    __shared__ u16 q_s[128 * 64];
    __shared__ u16 k_s[64 * 64];
    __shared__ u16 v_s[64 * 64];        // vt tile: rows d, cols y
    __shared__ u16 s_s[128 * 80];       // S tile (x rows, y cols), wave-private strips
    const int bid = blockIdx.x;
    const int bh = bid >> 3, x0 = (bid & 7) * 128;
    const int t = threadIdx.x;
    const int lane = t & 63, w = t >> 6, lm = lane & 15, lq = lane >> 4;
    const int sr = t >> 3, sc = (t & 7) * 8;

#pragma unroll
    for (int p = 0; p < 4; ++p)
        GLOAD16(&qb[(size_t)(bh * 1024 + x0 + p * 32 + sr) * 64 + sc],
                &q_s[p * 2048 + t * 8]);

    const u16* PqRow = Pq + ((size_t)(bh * 1024) + x0 + 32 * w + lm) * 1024 + lq * 4;
    f32x4 oacc[2][4] = {};
    for (int y0 = 0; y0 < 1024; y0 += 64) {
        // prefetch Pq fragments (global, C-layout: 4 consecutive y per lane)
        ushort4 pqr[4][2];
#pragma unroll
        for (int nt = 0; nt < 2; ++nt)
#pragma unroll
            for (int mt = 0; mt < 4; ++mt)
                pqr[mt][nt] = *(const ushort4*)&PqRow[(size_t)(nt * 16) * 1024 + y0 + mt * 16];
        __syncthreads();                       // k_s/v_s safe to overwrite
#pragma unroll
        for (int p = 0; p < 2; ++p) {
            GLOAD16(&kb[(size_t)(bh * 1024 + y0 + p * 32 + sr) * 64 + sc],
                    &k_s[p * 2048 + t * 8]);
            GLOAD16(&vt[(size_t)(bh * 64 + p * 32 + sr) * 1024 + y0 + sc],
                    &v_s[p * 2048 + t * 8]);
        }
        __syncthreads();                       // tiles ready (q_s too, first iter)
        // S^T = K.Q^T : D[y][x]; wave w owns x-strip [32w, 32w+32)
        f32x4 sacc[4][2] = {};
#pragma unroll
        for (int ks = 0; ks < 2; ++ks) {
            bf16x8 bq[2];
#pragma unroll
            for (int nt = 0; nt < 2; ++nt)
                bq[nt] = *(const bf16x8*)&q_s[(32 * w + nt * 16 + lm) * 64 + ks * 32 + lq * 8];
#pragma unroll
            for (int mt = 0; mt < 4; ++mt) {
                bf16x8 ak = *(const bf16x8*)&k_s[(mt * 16 + lm) * 64 + ks * 32 + lq * 8];
#pragma unroll
                for (int nt = 0; nt < 2; ++nt)
                    sacc[mt][nt] = MFMA16(ak, bq[nt], sacc[mt][nt]);
            }
        }
        // s = (qk + pq) * scale -> bf16 -> s_s (wave-private strip)
#pragma unroll
        for (int nt = 0; nt < 2; ++nt) {
            int xl = 32 * w + nt * 16 + lm;
#pragma unroll
            for (int mt = 0; mt < 4; ++mt) {
                ushort4 pq = pqr[mt][nt];
                ushort4 o;
                o.x = f2bf((sacc[mt][nt][0] + bf2f(pq.x)) * 0.125f);
                o.y = f2bf((sacc[mt][nt][1] + bf2f(pq.y)) * 0.125f);
                o.z = f2bf((sacc[mt][nt][2] + bf2f(pq.z)) * 0.125f);
                o.w = f2bf((sacc[mt][nt][3] + bf2f(pq.w)) * 0.125f);
                *(ushort4*)&s_s[xl * 80 + mt * 16 + lq * 4] = o;
            }
        }
        // O += S.V  (A = s_s own strip, B = v_s)
#pragma unroll
        for (int ks = 0; ks < 2; ++ks) {
            bf16x8 as[2];
#pragma unroll
            for (int mt = 0; mt < 2; ++mt)
                as[mt] = *(const bf16x8*)&s_s[(32 * w + mt * 16 + lm) * 80 + ks * 32 + lq * 8];
#pragma unroll
            for (int nt = 0; nt < 4; ++nt) {
                bf16x8 bv = *(const bf16x8*)&v_s[(nt * 16 + lm) * 64 + ks * 32 + lq * 8];
#pragma unroll
                for (int mt = 0; mt < 2; ++mt)
                    oacc[mt][nt] = MFMA16(as[mt], bv, oacc[mt][nt]);
            }
        }
    }
    // write attn (B, S, E=h*64+d) bf16
    const int b = bh >> 4, h = bh & 15;
    for (int mt = 0; mt < 2; ++mt) {
        for (int nt = 0; nt < 4; ++nt) {
            int d = nt * 16 + lm;
            for (int i = 0; i < 4; ++i) {
                int s = x0 + 32 * w + mt * 16 + lq * 4 + i;
                attnb[((size_t)(b * 1024 + s)) * 1024 + h * 64 + d] = f2bf(oacc[mt][nt][i]);
            }
        }
    }
}

// --------------------------------------------------------------------------
// Out projection (m97-style): out(4096x1024 fp32) = attn(bf16)@WoutT^T + b
// grid (8,32), block 256
// --------------------------------------------------------------------------
__global__ __launch_bounds__(256, 2) void kgemm_out(const u16* __restrict__ A,
                                                    const u16* __restrict__ WT,
                                                    const float* __restrict__ bias,
                                                    float* __restrict__ out) {
    __shared__ u16 a_s[128 * 64];
    __shared__ u16 b_s[128 * 64];
    const int t = threadIdx.x;
    const int m0 = blockIdx.y * 128, n0 = blockIdx.x * 128;
    const int lane = t & 63, w = t >> 6, lm = lane & 15, lq = lane >> 4;
    const int mb = (w >> 1) * 64, nb = (w & 1) * 64;
    const int sr = t >> 3, sc = (t & 7) * 8;

    f32x4 acc[4][4] = {};
    for (int k0 = 0; k0 < 1024; k0 += 64) {
        __syncthreads();
#pragma unroll
        for (int p = 0; p < 4; ++p) {
            GLOAD16(&A [(size_t)(m0 + p * 32 + sr) * 1024 + k0 + sc], &a_s[p * 2048 + t * 8]);
            GLOAD16(&WT[(size_t)(n0 + p * 32 + sr) * 1024 + k0 + sc], &b_s[p * 2048 + t * 8]);
        }
        __syncthreads();
#pragma unroll
        for (int ks = 0; ks < 2; ++ks) {
            bf16x8 af[4], bfr[4];
#pragma unroll
            for (int mt = 0; mt < 4; ++mt)
                af[mt] = *(const bf16x8*)&a_s[(mb + mt * 16 + lm) * 64 + ks * 32 + lq * 8];
#pragma unroll
            for (int nt = 0; nt < 4; ++nt)
                bfr[nt] = *(const bf16x8*)&b_s[(nb + nt * 16 + lm) * 64 + ks * 32 + lq * 8];
#pragma unroll
            for (int mt = 0; mt < 4; ++mt)
#pragma unroll
                for (int nt = 0; nt < 4; ++nt)
                    acc[mt][nt] = MFMA16(af[mt], bfr[nt], acc[mt][nt]);
        }
    }
    for (int nt = 0; nt < 4; ++nt) {
        int col = n0 + nb + nt * 16 + lm;
        float bv = bias[col];
        for (int mt = 0; mt < 4; ++mt) {
            for (int i = 0; i < 4; ++i) {
                int row = m0 + mb + mt * 16 + lq * 4 + i;
                out[(size_t)row * 1024 + col] = acc[mt][nt][i] + bv;
            }
        }
    }
}

// --------------------------------------------------------------------------
extern "C" void kernel_launch(void* const* d_in, const int* in_sizes, int n_in,
                              void* d_out, int out_size, void* d_ws, size_t ws_size,
                              hipStream_t stream) {
    (void)in_sizes; (void)n_in; (void)out_size; (void)ws_size;
    const float* x    = (const float*)d_in[0];
    const float* Wqkv = (const float*)d_in[1];
    const float* bqkv = (const float*)d_in[2];
    const float* pe   = (const float*)d_in[3];
    const float* Wout = (const float*)d_in[4];
    const float* bout = (const float*)d_in[5];
    float* out = (float*)d_out;

    char* ws = (char*)d_ws;
    u16* xb    = (u16*)ws;  ws += (size_t)4096 * 1024 * 2;     // 8 MB
    u16* wqkvT = (u16*)ws;  ws += (size_t)3072 * 1024 * 2;     // 6 MB
    u16* woutT = (u16*)ws;  ws += (size_t)1024 * 1024 * 2;     // 2 MB
    u16* qb    = (u16*)ws;  ws += (size_t)64 * 1024 * 64 * 2;  // 8 MB
    u16* kb    = (u16*)ws;  ws += (size_t)64 * 1024 * 64 * 2;  // 8 MB
    u16* vb    = (u16*)ws;  ws += (size_t)64 * 1024 * 64 * 2;  // 8 MB
    u16* vtb   = (u16*)ws;  ws += (size_t)64 * 64 * 1024 * 2;  // 8 MB
    u16* attnb = (u16*)ws;  ws += (size_t)4 * 1024 * 1024 * 2; // 8 MB
    u16* pq    = (u16*)ws;  ws += (size_t)64 * 1024 * 1024 * 2;// 128 MB

    kxconv<<<2048, 256, 0, stream>>>(x, xb);
    kconv_T<<<dim3(48, 16), 256, 0, stream>>>(Wqkv, wqkvT, 1024, 3072);
    kconv_T<<<dim3(16, 16), 256, 0, stream>>>(Wout, woutT, 1024, 1024);
    kgemm_qkv<<<dim3(24, 32), 256, 0, stream>>>(xb, wqkvT, bqkv, qb, kb, vb);
    ktrans_v<<<1024, 256, 0, stream>>>(vb, vtb);
    kpq<<<1024, 256, 0, stream>>>(qb, pe, pq);
    kattn<<<512, 256, 0, stream>>>(qb, kb, vtb, pq, attnb);
    kgemm_out<<<dim3(8, 32), 256, 0, stream>>>(attnb, woutT, bout, out);
}

// Round 3
// 530.256 us; speedup vs baseline: 1.1334x; 1.0246x over previous
//
#include <hip/hip_runtime.h>
#include <cstdint>
#include <cstddef>

// ---------------------------------------------------------------------------
// MultiHeadAttention (linear attention + relative position bias, no softmax)
// B=4 S=1024 E=1024 H=16 D=64.  bf16 MFMA pipeline, fp8 Pq intermediate:
//   1. kprep     : x->bf16 ; W_qkv,W_out -> bf16 transposed  (merged)
//   2. kgemm_qkv : qkv = x@Wqkv + b ; scatter q/k (bh,s,d), v DIRECT as vt (bh,d,s)
//   3. kpq       : Pq[bh][x][y] = sum_c pe[x,y,c]*q[bh,x,c]  -> fp8 e4m3
//   4. kattn     : O = ((QK^T + Pq)*scale) @ V  (Pq read direct in C-layout, fp8)
//                  grid bid = xt*64+bh -> all x-tiles of a bh on one XCD (k/v L2 reuse)
//   5. kgemm_out : out = attn@Wout + b (fp32)
// ---------------------------------------------------------------------------

typedef unsigned short u16;
typedef unsigned char  u8;
typedef __bf16 bf16x8 __attribute__((ext_vector_type(8)));
typedef float  f32x4  __attribute__((ext_vector_type(4)));
typedef unsigned short u16x8 __attribute__((ext_vector_type(8)));

#define MFMA16(a, b, c) __builtin_amdgcn_mfma_f32_16x16x32_bf16((a), (b), (c), 0, 0, 0)

// async global->LDS, 16 B per lane; LDS dest = wave-uniform base + lane*16
#define GLOAD16(g, l)                                                        \
    __builtin_amdgcn_global_load_lds(                                        \
        (const __attribute__((address_space(1))) unsigned int*)(g),          \
        (__attribute__((address_space(3))) unsigned int*)(l), 16, 0, 0)

__device__ __forceinline__ u16 f2bf(float f) {
    __bf16 h = (__bf16)f;
    return __builtin_bit_cast(u16, h);
}
__device__ __forceinline__ u16x8 pack8(float4 a, float4 b) {
    u16x8 v;
    v[0] = f2bf(a.x); v[1] = f2bf(a.y); v[2] = f2bf(a.z); v[3] = f2bf(a.w);
    v[4] = f2bf(b.x); v[5] = f2bf(b.y); v[6] = f2bf(b.z); v[7] = f2bf(b.w);
    return v;
}

// --------------------------------------------------------------------------
// Merged prep: blocks [0,2048): x fp32->bf16 (8 elem/thread)
//              blocks [2048,2816): Wqkv (1024x3072) -> wqkvT (3072x1024) bf16
//              blocks [2816,3072): Wout (1024x1024) -> woutT bf16
// --------------------------------------------------------------------------
__device__ __forceinline__ void convT_tile(const float* __restrict__ in,
                                           u16* __restrict__ out, int R, int C,
                                           int bx, int by, float (*tile)[68]) {
    const int t  = threadIdx.x;
    const int r0 = by * 64, c0 = bx * 64;
    const int rr = t >> 4, c4 = t & 15;
    for (int p = 0; p < 4; ++p) {
        int r = rr + p * 16;
        float4 v = *(const float4*)&in[(size_t)(r0 + r) * C + c0 + c4 * 4];
        *(float4*)&tile[r][c4 * 4] = v;
    }
    __syncthreads();
    for (int p = 0; p < 4; ++p) {
        int n = rr + p * 16;
        ushort4 o;
        o.x = f2bf(tile[c4 * 4 + 0][n]);
        o.y = f2bf(tile[c4 * 4 + 1][n]);
        o.z = f2bf(tile[c4 * 4 + 2][n]);
        o.w = f2bf(tile[c4 * 4 + 3][n]);
        *(ushort4*)&out[(size_t)(c0 + n) * R + r0 + c4 * 4] = o;
    }
}

__global__ __launch_bounds__(256) void kprep(const float* __restrict__ x,
                                             u16* __restrict__ xb,
                                             const float* __restrict__ Wqkv,
                                             u16* __restrict__ wqkvT,
                                             const float* __restrict__ Wout,
                                             u16* __restrict__ woutT) {
    __shared__ float tile[64][68];
    const int bid = blockIdx.x;
    if (bid < 2048) {
        int i = (bid * 256 + threadIdx.x) * 8;
        float4 f0 = *(const float4*)&x[i];
        float4 f1 = *(const float4*)&x[i + 4];
        *(u16x8*)&xb[i] = pack8(f0, f1);
    } else if (bid < 2816) {
        int r = bid - 2048;                       // 48 x 16
        convT_tile(Wqkv, wqkvT, 1024, 3072, r % 48, r / 48, tile);
    } else {
        int r = bid - 2816;                       // 16 x 16
        convT_tile(Wout, woutT, 1024, 1024, r % 16, r / 16, tile);
    }
}

// --------------------------------------------------------------------------
// QKV GEMM (m97-style): C(4096x3072) = Xb(bf16) @ WT(3072x1024)^T + bias
// Epilogue: q,k -> (bh,s,d) scatter; v -> vt (bh,d,s) DIRECT (ushort4, C-layout
// gives 4 consecutive s per lane).  grid (24,32), block 256
// --------------------------------------------------------------------------
__global__ __launch_bounds__(256, 2) void kgemm_qkv(const u16* __restrict__ A,
                                                    const u16* __restrict__ WT,
                                                    const float* __restrict__ bias,
                                                    u16* __restrict__ qb,
                                                    u16* __restrict__ kb,
                                                    u16* __restrict__ vtb) {
    __shared__ u16 a_s[128 * 64];
    __shared__ u16 b_s[128 * 64];
    const int t = threadIdx.x;
    const int m0 = blockIdx.y * 128, n0 = blockIdx.x * 128;
    const int lane = t & 63, w = t >> 6, lm = lane & 15, lq = lane >> 4;
    const int mb = (w >> 1) * 64, nb = (w & 1) * 64;
    const int sr = t >> 3, sc = (t & 7) * 8;

    f32x4 acc[4][4] = {};
    for (int k0 = 0; k0 < 1024; k0 += 64) {
        __syncthreads();
#pragma unroll
        for (int p = 0; p < 4; ++p) {
            GLOAD16(&A [(size_t)(m0 + p * 32 + sr) * 1024 + k0 + sc], &a_s[p * 2048 + t * 8]);
            GLOAD16(&WT[(size_t)(n0 + p * 32 + sr) * 1024 + k0 + sc], &b_s[p * 2048 + t * 8]);
        }
        __syncthreads();
#pragma unroll
        for (int ks = 0; ks < 2; ++ks) {
            bf16x8 af[4], bfr[4];
#pragma unroll
            for (int mt = 0; mt < 4; ++mt)
                af[mt] = *(const bf16x8*)&a_s[(mb + mt * 16 + lm) * 64 + ks * 32 + lq * 8];
#pragma unroll
            for (int nt = 0; nt < 4; ++nt)
                bfr[nt] = *(const bf16x8*)&b_s[(nb + nt * 16 + lm) * 64 + ks * 32 + lq * 8];
#pragma unroll
            for (int mt = 0; mt < 4; ++mt)
#pragma unroll
                for (int nt = 0; nt < 4; ++nt)
                    acc[mt][nt] = MFMA16(af[mt], bfr[nt], acc[mt][nt]);
        }
    }
    for (int nt = 0; nt < 4; ++nt) {
        int col = n0 + nb + nt * 16 + lm;
        float bv = bias[col];
        int which = col >> 10;
        int h = (col >> 6) & 15, d = col & 63;
        for (int mt = 0; mt < 4; ++mt) {
            int row0 = m0 + mb + mt * 16 + lq * 4;
            int b = row0 >> 10, s = row0 & 1023;
            if (which == 2) {                     // vt[bh][d][s] coalesced ushort4
                ushort4 o;
                o.x = f2bf(acc[mt][nt][0] + bv);
                o.y = f2bf(acc[mt][nt][1] + bv);
                o.z = f2bf(acc[mt][nt][2] + bv);
                o.w = f2bf(acc[mt][nt][3] + bv);
                *(ushort4*)&vtb[((size_t)(b * 16 + h) * 64 + d) * 1024 + s] = o;
            } else {
                u16* dst = (which == 0) ? qb : kb;
                for (int i = 0; i < 4; ++i)
                    dst[((size_t)((b * 16 + h) * 1024 + s + i)) * 64 + d] =
                        f2bf(acc[mt][nt][i] + bv);
            }
        }
    }
}

// --------------------------------------------------------------------------
// Pq[bh][x][y] = sum_c pe[x,y,c]*q[bh,x,c] -> fp8 e4m3 (scale applied in kattn)
// One block per x; pe streamed once device-wide; register prefetch of next
// chunk; single pe_s/o_s buffers (23 KB LDS -> high occupancy).
// grid 1024, block 256
// --------------------------------------------------------------------------
__global__ __launch_bounds__(256, 4) void kpq(const u16* __restrict__ qb,
                                              const float* __restrict__ pe,
                                              u8* __restrict__ Pq) {
    __shared__ u16 q_s[64 * 64];
    __shared__ u16 pe_s[64 * 80];
    __shared__ unsigned int o_s[64 * 17];   // fp8: 64 bh x 16 u32 (64 y), pad 17
    const int x = blockIdx.x;
    const int t = threadIdx.x;
    const int lane = t & 63, w = t >> 6, lm = lane & 15, lq = lane >> 4;
#pragma unroll
    for (int p = 0; p < 2; ++p)
        GLOAD16(&qb[(size_t)((p * 32 + (t >> 3)) * 1024 + x) * 64 + (t & 7) * 8],
                &q_s[p * 2048 + t * 8]);
    const int yl = t >> 2, cq = (t & 3) * 16;
    const float* pex = pe + (size_t)x * 65536;
    float4 r0, r1, r2, r3;
    {
        const float* src = &pex[(size_t)yl * 64 + cq];
        r0 = *(const float4*)&src[0];  r1 = *(const float4*)&src[4];
        r2 = *(const float4*)&src[8];  r3 = *(const float4*)&src[12];
    }
    const int obh = t >> 2, oyc = t & 3;
    for (int it = 0; it < 16; ++it) {
        *(u16x8*)&pe_s[yl * 80 + cq]     = pack8(r0, r1);
        *(u16x8*)&pe_s[yl * 80 + cq + 8] = pack8(r2, r3);
        __syncthreads();                        // pe_s ready (covers q_s on it=0)
        if (it < 15) {                          // prefetch next chunk
            const float* src = &pex[(size_t)((it + 1) * 64 + yl) * 64 + cq];
            r0 = *(const float4*)&src[0];  r1 = *(const float4*)&src[4];
            r2 = *(const float4*)&src[8];  r3 = *(const float4*)&src[12];
        }
        // D[y][bh]: wave w owns y-strip [16w, 16w+16)
        f32x4 acc[4] = {};
#pragma unroll
        for (int ks = 0; ks < 2; ++ks) {
            bf16x8 a = *(const bf16x8*)&pe_s[(16 * w + lm) * 80 + ks * 32 + lq * 8];
#pragma unroll
            for (int nt = 0; nt < 4; ++nt) {
                bf16x8 b = *(const bf16x8*)&q_s[(nt * 16 + lm) * 64 + ks * 32 + lq * 8];
                acc[nt] = MFMA16(a, b, acc[nt]);
            }
        }
#pragma unroll
        for (int nt = 0; nt < 4; ++nt) {        // 4 y (consecutive) -> packed fp8
            unsigned int pw;
            pw = __builtin_amdgcn_cvt_pk_fp8_f32(acc[nt][0], acc[nt][1], 0u, false);
            pw = __builtin_amdgcn_cvt_pk_fp8_f32(acc[nt][2], acc[nt][3], pw, true);
            o_s[(nt * 16 + lm) * 17 + 4 * w + lq] = pw;
        }
        __syncthreads();                        // o_s ready; pe_s reads done
        uint4 dv;
        dv.x = o_s[obh * 17 + oyc * 4 + 0];
        dv.y = o_s[obh * 17 + oyc * 4 + 1];
        dv.z = o_s[obh * 17 + oyc * 4 + 2];
        dv.w = o_s[obh * 17 + oyc * 4 + 3];
        *(uint4*)&Pq[((size_t)obh * 1024 + x) * 1024 + it * 64 + oyc * 16] = dv;
    }
}

// --------------------------------------------------------------------------
// Fused attention: O[x,d] = sum_y (q_x.k_y + Pq[x,y])*scale * v[y,d]
// bid = xt*64 + bh  ->  bid%8 = bh%8: all 8 x-tiles of a bh on one XCD
// (k/v served from L2 after first block).  Pq read direct (fp8, C-layout).
// grid 512, block 256
// --------------------------------------------------------------------------
__global__ __launch_bounds__(256, 2) void kattn(const u16* __restrict__ qb,
                                                const u16* __restrict__ kb,
                                                const u16* __restrict__ vt,
                                                const u8* __restrict__ Pq,
                                                u16* __restrict__ attnb) {
    __shared__ u16 q_s[128 * 64];
    __shared__ u16 k_s[64 * 64];
    __shared__ u16 v_s[64 * 64];        // vt tile: rows d, cols y
    __shared__ u16 s_s[128 * 80];       // S tile (x rows, y cols), wave-private strips
    const int bid = blockIdx.x;
    const int bh = bid & 63, x0 = (bid >> 6) * 128;
    const int t = threadIdx.x;
    const int lane = t & 63, w = t >> 6, lm = lane & 15, lq = lane >> 4;
    const int sr = t >> 3, sc = (t & 7) * 8;

#pragma unroll
    for (int p = 0; p < 4; ++p)
        GLOAD16(&qb[(size_t)(bh * 1024 + x0 + p * 32 + sr) * 64 + sc],
                &q_s[p * 2048 + t * 8]);

    const u8* PqRow = Pq + ((size_t)(bh * 1024) + x0 + 32 * w + lm) * 1024 + lq * 4;
    f32x4 oacc[2][4] = {};
    for (int y0 = 0; y0 < 1024; y0 += 64) {
        // prefetch Pq fragments (fp8, 4 consecutive y per lane per (mt,nt))
        unsigned int pqr[4][2];
#pragma unroll
        for (int nt = 0; nt < 2; ++nt)
#pragma unroll
            for (int mt = 0; mt < 4; ++mt)
                pqr[mt][nt] = *(const unsigned int*)&PqRow[(size_t)(nt * 16) * 1024 + y0 + mt * 16];
        __syncthreads();                       // k_s/v_s safe to overwrite
#pragma unroll
        for (int p = 0; p < 2; ++p) {
            GLOAD16(&kb[(size_t)(bh * 1024 + y0 + p * 32 + sr) * 64 + sc],
                    &k_s[p * 2048 + t * 8]);
            GLOAD16(&vt[(size_t)(bh * 64 + p * 32 + sr) * 1024 + y0 + sc],
                    &v_s[p * 2048 + t * 8]);
        }
        __syncthreads();                       // tiles ready (q_s too, first iter)
        // S^T = K.Q^T : D[y][x]; wave w owns x-strip [32w, 32w+32)
        f32x4 sacc[4][2] = {};
#pragma unroll
        for (int ks = 0; ks < 2; ++ks) {
            bf16x8 bq[2];
#pragma unroll
            for (int nt = 0; nt < 2; ++nt)
                bq[nt] = *(const bf16x8*)&q_s[(32 * w + nt * 16 + lm) * 64 + ks * 32 + lq * 8];
#pragma unroll
            for (int mt = 0; mt < 4; ++mt) {
                bf16x8 ak = *(const bf16x8*)&k_s[(mt * 16 + lm) * 64 + ks * 32 + lq * 8];
#pragma unroll
                for (int nt = 0; nt < 2; ++nt)
                    sacc[mt][nt] = MFMA16(ak, bq[nt], sacc[mt][nt]);
            }
        }
        // s = (qk + pq) * scale -> bf16 -> s_s (wave-private strip)
#pragma unroll
        for (int nt = 0; nt < 2; ++nt) {
            int xl = 32 * w + nt * 16 + lm;
#pragma unroll
            for (int mt = 0; mt < 4; ++mt) {
                unsigned int pw = pqr[mt][nt];
                ushort4 o;
                o.x = f2bf((sacc[mt][nt][0] + __builtin_amdgcn_cvt_f32_fp8(pw, 0)) * 0.125f);
                o.y = f2bf((sacc[mt][nt][1] + __builtin_amdgcn_cvt_f32_fp8(pw, 1)) * 0.125f);
                o.z = f2bf((sacc[mt][nt][2] + __builtin_amdgcn_cvt_f32_fp8(pw, 2)) * 0.125f);
                o.w = f2bf((sacc[mt][nt][3] + __builtin_amdgcn_cvt_f32_fp8(pw, 3)) * 0.125f);
                *(ushort4*)&s_s[xl * 80 + mt * 16 + lq * 4] = o;
            }
        }
        // O += S.V  (A = s_s own strip, B = v_s)
#pragma unroll
        for (int ks = 0; ks < 2; ++ks) {
            bf16x8 as[2];
#pragma unroll
            for (int mt = 0; mt < 2; ++mt)
                as[mt] = *(const bf16x8*)&s_s[(32 * w + mt * 16 + lm) * 80 + ks * 32 + lq * 8];
#pragma unroll
            for (int nt = 0; nt < 4; ++nt) {
                bf16x8 bv = *(const bf16x8*)&v_s[(nt * 16 + lm) * 64 + ks * 32 + lq * 8];
#pragma unroll
                for (int mt = 0; mt < 2; ++mt)
                    oacc[mt][nt] = MFMA16(as[mt], bv, oacc[mt][nt]);
            }
        }
    }
    // write attn (B, S, E=h*64+d) bf16
    const int b = bh >> 4, h = bh & 15;
    for (int mt = 0; mt < 2; ++mt) {
        for (int nt = 0; nt < 4; ++nt) {
            int d = nt * 16 + lm;
            for (int i = 0; i < 4; ++i) {
                int s = x0 + 32 * w + mt * 16 + lq * 4 + i;
                attnb[((size_t)(b * 1024 + s)) * 1024 + h * 64 + d] = f2bf(oacc[mt][nt][i]);
            }
        }
    }
}

// --------------------------------------------------------------------------
// Out projection (m97-style): out(4096x1024 fp32) = attn(bf16)@WoutT^T + b
// grid (8,32), block 256
// --------------------------------------------------------------------------
__global__ __launch_bounds__(256, 2) void kgemm_out(const u16* __restrict__ A,
                                                    const u16* __restrict__ WT,
                                                    const float* __restrict__ bias,
                                                    float* __restrict__ out) {
    __shared__ u16 a_s[128 * 64];
    __shared__ u16 b_s[128 * 64];
    const int t = threadIdx.x;
    const int m0 = blockIdx.y * 128, n0 = blockIdx.x * 128;
    const int lane = t & 63, w = t >> 6, lm = lane & 15, lq = lane >> 4;
    const int mb = (w >> 1) * 64, nb = (w & 1) * 64;
    const int sr = t >> 3, sc = (t & 7) * 8;

    f32x4 acc[4][4] = {};
    for (int k0 = 0; k0 < 1024; k0 += 64) {
        __syncthreads();
#pragma unroll
        for (int p = 0; p < 4; ++p) {
            GLOAD16(&A [(size_t)(m0 + p * 32 + sr) * 1024 + k0 + sc], &a_s[p * 2048 + t * 8]);
            GLOAD16(&WT[(size_t)(n0 + p * 32 + sr) * 1024 + k0 + sc], &b_s[p * 2048 + t * 8]);
        }
        __syncthreads();
#pragma unroll
        for (int ks = 0; ks < 2; ++ks) {
            bf16x8 af[4], bfr[4];
#pragma unroll
            for (int mt = 0; mt < 4; ++mt)
                af[mt] = *(const bf16x8*)&a_s[(mb + mt * 16 + lm) * 64 + ks * 32 + lq * 8];
#pragma unroll
            for (int nt = 0; nt < 4; ++nt)
                bfr[nt] = *(const bf16x8*)&b_s[(nb + nt * 16 + lm) * 64 + ks * 32 + lq * 8];
#pragma unroll
            for (int mt = 0; mt < 4; ++mt)
#pragma unroll
                for (int nt = 0; nt < 4; ++nt)
                    acc[mt][nt] = MFMA16(af[mt], bfr[nt], acc[mt][nt]);
        }
    }
    for (int nt = 0; nt < 4; ++nt) {
        int col = n0 + nb + nt * 16 + lm;
        float bv = bias[col];
        for (int mt = 0; mt < 4; ++mt) {
            for (int i = 0; i < 4; ++i) {
                int row = m0 + mb + mt * 16 + lq * 4 + i;
                out[(size_t)row * 1024 + col] = acc[mt][nt][i] + bv;
            }
        }
    }
}

// --------------------------------------------------------------------------
extern "C" void kernel_launch(void* const* d_in, const int* in_sizes, int n_in,
                              void* d_out, int out_size, void* d_ws, size_t ws_size,
                              hipStream_t stream) {
    (void)in_sizes; (void)n_in; (void)out_size; (void)ws_size;
    const float* x    = (const float*)d_in[0];
    const float* Wqkv = (const float*)d_in[1];
    const float* bqkv = (const float*)d_in[2];
    const float* pe   = (const float*)d_in[3];
    const float* Wout = (const float*)d_in[4];
    const float* bout = (const float*)d_in[5];
    float* out = (float*)d_out;

    char* ws = (char*)d_ws;
    u16* xb    = (u16*)ws;  ws += (size_t)4096 * 1024 * 2;     // 8 MB
    u16* wqkvT = (u16*)ws;  ws += (size_t)3072 * 1024 * 2;     // 6 MB
    u16* woutT = (u16*)ws;  ws += (size_t)1024 * 1024 * 2;     // 2 MB
    u16* qb    = (u16*)ws;  ws += (size_t)64 * 1024 * 64 * 2;  // 8 MB
    u16* kb    = (u16*)ws;  ws += (size_t)64 * 1024 * 64 * 2;  // 8 MB
    u16* vtb   = (u16*)ws;  ws += (size_t)64 * 64 * 1024 * 2;  // 8 MB
    u16* attnb = (u16*)ws;  ws += (size_t)4 * 1024 * 1024 * 2; // 8 MB
    u8*  pq    = (u8*)ws;   ws += (size_t)64 * 1024 * 1024;    // 64 MB (fp8)

    kprep<<<3072, 256, 0, stream>>>(x, xb, Wqkv, wqkvT, Wout, woutT);
    kgemm_qkv<<<dim3(24, 32), 256, 0, stream>>>(xb, wqkvT, bqkv, qb, kb, vtb);
    kpq<<<1024, 256, 0, stream>>>(qb, pe, pq);
    kattn<<<512, 256, 0, stream>>>(qb, kb, vtb, pq, attnb);
    kgemm_out<<<dim3(8, 32), 256, 0, stream>>>(attnb, woutT, bout, out);
}

// Round 4
// 522.041 us; speedup vs baseline: 1.1512x; 1.0157x over previous
//
#include <hip/hip_runtime.h>
#include <cstdint>
#include <cstddef>

// ---------------------------------------------------------------------------
// MultiHeadAttention (linear attention + relative position bias, no softmax)
// B=4 S=1024 E=1024 H=16 D=64.  bf16 MFMA pipeline, fp8 Pq intermediate:
//   1. kprep     : x->bf16 ; W_qkv,W_out -> bf16 transposed  (merged)
//   2. kgemm_qkv : qkv = x@Wqkv + b ; scatter q/k (bh,s,d), v DIRECT as vt (bh,d,s)
//   3. kpq       : Pq[bh][x][y] = sum_c pe[x,y,c]*q[bh,x,c] -> fp8, stored
//                  DIRECT from MFMA ACC fragments in permuted-y order
//                  (per 64-y group: byte off = lq*16 + w*4 + i, y = w*16+lq*4+i)
//   4. kattn     : O = ((QK^T + Pq)*scale) @ V ; Pq read as ONE uint4/lane per
//                  (nt,y0) — component mt = y's {y0+mt*16+lq*4..+3}
//   5. kgemm_out : out = attn@Wout + b (fp32)
// NOTE: ~390 us of dur_us is harness per-iteration overhead (1 GB ws poison +
// input restore); kernel-side total is ~140 us vs ~95 us floor.
// ---------------------------------------------------------------------------

typedef unsigned short u16;
typedef unsigned char  u8;
typedef __bf16 bf16x8 __attribute__((ext_vector_type(8)));
typedef float  f32x4  __attribute__((ext_vector_type(4)));
typedef unsigned short u16x8 __attribute__((ext_vector_type(8)));

#define MFMA16(a, b, c) __builtin_amdgcn_mfma_f32_16x16x32_bf16((a), (b), (c), 0, 0, 0)

// async global->LDS, 16 B per lane; LDS dest = wave-uniform base + lane*16
#define GLOAD16(g, l)                                                        \
    __builtin_amdgcn_global_load_lds(                                        \
        (const __attribute__((address_space(1))) unsigned int*)(g),          \
        (__attribute__((address_space(3))) unsigned int*)(l), 16, 0, 0)

__device__ __forceinline__ u16 f2bf(float f) {
    __bf16 h = (__bf16)f;
    return __builtin_bit_cast(u16, h);
}
__device__ __forceinline__ u16x8 pack8(float4 a, float4 b) {
    u16x8 v;
    v[0] = f2bf(a.x); v[1] = f2bf(a.y); v[2] = f2bf(a.z); v[3] = f2bf(a.w);
    v[4] = f2bf(b.x); v[5] = f2bf(b.y); v[6] = f2bf(b.z); v[7] = f2bf(b.w);
    return v;
}

// --------------------------------------------------------------------------
// Merged prep: blocks [0,2048): x fp32->bf16 (8 elem/thread)
//              blocks [2048,2816): Wqkv (1024x3072) -> wqkvT (3072x1024) bf16
//              blocks [2816,3072): Wout (1024x1024) -> woutT bf16
// --------------------------------------------------------------------------
__device__ __forceinline__ void convT_tile(const float* __restrict__ in,
                                           u16* __restrict__ out, int R, int C,
                                           int bx, int by, float (*tile)[68]) {
    const int t  = threadIdx.x;
    const int r0 = by * 64, c0 = bx * 64;
    const int rr = t >> 4, c4 = t & 15;
    for (int p = 0; p < 4; ++p) {
        int r = rr + p * 16;
        float4 v = *(const float4*)&in[(size_t)(r0 + r) * C + c0 + c4 * 4];
        *(float4*)&tile[r][c4 * 4] = v;
    }
    __syncthreads();
    for (int p = 0; p < 4; ++p) {
        int n = rr + p * 16;
        ushort4 o;
        o.x = f2bf(tile[c4 * 4 + 0][n]);
        o.y = f2bf(tile[c4 * 4 + 1][n]);
        o.z = f2bf(tile[c4 * 4 + 2][n]);
        o.w = f2bf(tile[c4 * 4 + 3][n]);
        *(ushort4*)&out[(size_t)(c0 + n) * R + r0 + c4 * 4] = o;
    }
}

__global__ __launch_bounds__(256) void kprep(const float* __restrict__ x,
                                             u16* __restrict__ xb,
                                             const float* __restrict__ Wqkv,
                                             u16* __restrict__ wqkvT,
                                             const float* __restrict__ Wout,
                                             u16* __restrict__ woutT) {
    __shared__ float tile[64][68];
    const int bid = blockIdx.x;
    if (bid < 2048) {
        int i = (bid * 256 + threadIdx.x) * 8;
        float4 f0 = *(const float4*)&x[i];
        float4 f1 = *(const float4*)&x[i + 4];
        *(u16x8*)&xb[i] = pack8(f0, f1);
    } else if (bid < 2816) {
        int r = bid - 2048;                       // 48 x 16
        convT_tile(Wqkv, wqkvT, 1024, 3072, r % 48, r / 48, tile);
    } else {
        int r = bid - 2816;                       // 16 x 16
        convT_tile(Wout, woutT, 1024, 1024, r % 16, r / 16, tile);
    }
}

// --------------------------------------------------------------------------
// QKV GEMM (m97-style): C(4096x3072) = Xb(bf16) @ WT(3072x1024)^T + bias
// Epilogue: q,k -> (bh,s,d) scatter; v -> vt (bh,d,s) DIRECT (ushort4).
// grid (24,32), block 256
// --------------------------------------------------------------------------
__global__ __launch_bounds__(256, 2) void kgemm_qkv(const u16* __restrict__ A,
                                                    const u16* __restrict__ WT,
                                                    const float* __restrict__ bias,
                                                    u16* __restrict__ qb,
                                                    u16* __restrict__ kb,
                                                    u16* __restrict__ vtb) {
    __shared__ u16 a_s[128 * 64];
    __shared__ u16 b_s[128 * 64];
    const int t = threadIdx.x;
    const int m0 = blockIdx.y * 128, n0 = blockIdx.x * 128;
    const int lane = t & 63, w = t >> 6, lm = lane & 15, lq = lane >> 4;
    const int mb = (w >> 1) * 64, nb = (w & 1) * 64;
    const int sr = t >> 3, sc = (t & 7) * 8;

    f32x4 acc[4][4] = {};
    for (int k0 = 0; k0 < 1024; k0 += 64) {
        __syncthreads();
#pragma unroll
        for (int p = 0; p < 4; ++p) {
            GLOAD16(&A [(size_t)(m0 + p * 32 + sr) * 1024 + k0 + sc], &a_s[p * 2048 + t * 8]);
            GLOAD16(&WT[(size_t)(n0 + p * 32 + sr) * 1024 + k0 + sc], &b_s[p * 2048 + t * 8]);
        }
        __syncthreads();
#pragma unroll
        for (int ks = 0; ks < 2; ++ks) {
            bf16x8 af[4], bfr[4];
#pragma unroll
            for (int mt = 0; mt < 4; ++mt)
                af[mt] = *(const bf16x8*)&a_s[(mb + mt * 16 + lm) * 64 + ks * 32 + lq * 8];
#pragma unroll
            for (int nt = 0; nt < 4; ++nt)
                bfr[nt] = *(const bf16x8*)&b_s[(nb + nt * 16 + lm) * 64 + ks * 32 + lq * 8];
#pragma unroll
            for (int mt = 0; mt < 4; ++mt)
#pragma unroll
                for (int nt = 0; nt < 4; ++nt)
                    acc[mt][nt] = MFMA16(af[mt], bfr[nt], acc[mt][nt]);
        }
    }
    for (int nt = 0; nt < 4; ++nt) {
        int col = n0 + nb + nt * 16 + lm;
        float bv = bias[col];
        int which = col >> 10;
        int h = (col >> 6) & 15, d = col & 63;
        for (int mt = 0; mt < 4; ++mt) {
            int row0 = m0 + mb + mt * 16 + lq * 4;
            int b = row0 >> 10, s = row0 & 1023;
            if (which == 2) {                     // vt[bh][d][s] coalesced ushort4
                ushort4 o;
                o.x = f2bf(acc[mt][nt][0] + bv);
                o.y = f2bf(acc[mt][nt][1] + bv);
                o.z = f2bf(acc[mt][nt][2] + bv);
                o.w = f2bf(acc[mt][nt][3] + bv);
                *(ushort4*)&vtb[((size_t)(b * 16 + h) * 64 + d) * 1024 + s] = o;
            } else {
                u16* dst = (which == 0) ? qb : kb;
                for (int i = 0; i < 4; ++i)
                    dst[((size_t)((b * 16 + h) * 1024 + s + i)) * 64 + d] =
                        f2bf(acc[mt][nt][i] + bv);
            }
        }
    }
}

// --------------------------------------------------------------------------
// Pq[bh][x][y] = sum_c pe[x,y,c]*q[bh,x,c] -> fp8 e4m3 (scale in kattn)
// One block per x; pe streamed once device-wide; double-buffered pe_s,
// ONE barrier/iter; output stored DIRECT from ACC fragments:
//   byte offset within 64-y group = lq*16 + w*4 + i  (y = w*16 + lq*4 + i)
// grid 1024, block 256
// --------------------------------------------------------------------------
__global__ __launch_bounds__(256, 4) void kpq(const u16* __restrict__ qb,
                                              const float* __restrict__ pe,
                                              u8* __restrict__ Pq) {
    __shared__ u16 q_s[64 * 64];
    __shared__ u16 pe_s[2][64 * 80];
    const int x = blockIdx.x;
    const int t = threadIdx.x;
    const int lane = t & 63, w = t >> 6, lm = lane & 15, lq = lane >> 4;
#pragma unroll
    for (int p = 0; p < 2; ++p)
        GLOAD16(&qb[(size_t)((p * 32 + (t >> 3)) * 1024 + x) * 64 + (t & 7) * 8],
                &q_s[p * 2048 + t * 8]);
    const int yl = t >> 2, cq = (t & 3) * 16;
    const float* pex = pe + (size_t)x * 65536;
    float4 r0, r1, r2, r3;
    {
        const float* src = &pex[(size_t)yl * 64 + cq];
        r0 = *(const float4*)&src[0];  r1 = *(const float4*)&src[4];
        r2 = *(const float4*)&src[8];  r3 = *(const float4*)&src[12];
    }
    // per-lane fragment store base: bh = nt*16+lm, row x, group byte lq*16+w*4
    u8* pq_base = Pq + ((size_t)lm * 1024 + x) * 1024 + lq * 16 + w * 4;
    int cur = 0;
    for (int it = 0; it < 16; ++it) {
        *(u16x8*)&pe_s[cur][yl * 80 + cq]     = pack8(r0, r1);
        *(u16x8*)&pe_s[cur][yl * 80 + cq + 8] = pack8(r2, r3);
        __syncthreads();                        // pe_s[cur] ready (covers q_s on it=0)
        if (it < 15) {                          // prefetch next chunk
            const float* src = &pex[(size_t)((it + 1) * 64 + yl) * 64 + cq];
            r0 = *(const float4*)&src[0];  r1 = *(const float4*)&src[4];
            r2 = *(const float4*)&src[8];  r3 = *(const float4*)&src[12];
        }
        // D[y][bh]: wave w owns y-strip [16w, 16w+16)
        f32x4 acc[4] = {};
#pragma unroll
        for (int ks = 0; ks < 2; ++ks) {
            bf16x8 a = *(const bf16x8*)&pe_s[cur][(16 * w + lm) * 80 + ks * 32 + lq * 8];
#pragma unroll
            for (int nt = 0; nt < 4; ++nt) {
                bf16x8 b = *(const bf16x8*)&q_s[(nt * 16 + lm) * 64 + ks * 32 + lq * 8];
                acc[nt] = MFMA16(a, b, acc[nt]);
            }
        }
        // store fragments direct: lane holds bh=nt*16+lm, 4 consecutive y
#pragma unroll
        for (int nt = 0; nt < 4; ++nt) {
            unsigned int pw;
            pw = __builtin_amdgcn_cvt_pk_fp8_f32(acc[nt][0], acc[nt][1], 0u, false);
            pw = __builtin_amdgcn_cvt_pk_fp8_f32(acc[nt][2], acc[nt][3], pw, true);
            *(unsigned int*)&pq_base[(size_t)nt * 16 * 1024 * 1024 + it * 64] = pw;
        }
        cur ^= 1;
    }
}

// --------------------------------------------------------------------------
// Fused attention: O[x,d] = sum_y (q_x.k_y + Pq[x,y])*scale * v[y,d]
// bid = xt*64 + bh  ->  bid%8 = bh%8: all 8 x-tiles of a bh on one XCD.
// Pq: ONE uint4 per (nt,y0) per lane; component mt = y {y0+mt*16+lq*4..+3}.
// grid 512, block 256
// --------------------------------------------------------------------------
__global__ __launch_bounds__(256, 2) void kattn(const u16* __restrict__ qb,
                                                const u16* __restrict__ kb,
                                                const u16* __restrict__ vt,
                                                const u8* __restrict__ Pq,
                                                u16* __restrict__ attnb) {
    __shared__ u16 q_s[128 * 64];
    __shared__ u16 k_s[64 * 64];
    __shared__ u16 v_s[64 * 64];        // vt tile: rows d, cols y
    __shared__ u16 s_s[128 * 80];       // S tile (x rows, y cols), wave-private strips
    const int bid = blockIdx.x;
    const int bh = bid & 63, x0 = (bid >> 6) * 128;
    const int t = threadIdx.x;
    const int lane = t & 63, w = t >> 6, lm = lane & 15, lq = lane >> 4;
    const int sr = t >> 3, sc = (t & 7) * 8;

#pragma unroll
    for (int p = 0; p < 4; ++p)
        GLOAD16(&qb[(size_t)(bh * 1024 + x0 + p * 32 + sr) * 64 + sc],
                &q_s[p * 2048 + t * 8]);

    const u8* PqRow = Pq + ((size_t)(bh * 1024) + x0 + 32 * w + lm) * 1024 + lq * 16;
    f32x4 oacc[2][4] = {};
    for (int y0 = 0; y0 < 1024; y0 += 64) {
        // prefetch Pq fragments: one uint4 per nt (x-row = x0+32w+nt*16+lm)
        uint4 pq4[2];
#pragma unroll
        for (int nt = 0; nt < 2; ++nt)
            pq4[nt] = *(const uint4*)&PqRow[(size_t)(nt * 16) * 1024 + y0];
        __syncthreads();                       // k_s/v_s safe to overwrite
#pragma unroll
        for (int p = 0; p < 2; ++p) {
            GLOAD16(&kb[(size_t)(bh * 1024 + y0 + p * 32 + sr) * 64 + sc],
                    &k_s[p * 2048 + t * 8]);
            GLOAD16(&vt[(size_t)(bh * 64 + p * 32 + sr) * 1024 + y0 + sc],
                    &v_s[p * 2048 + t * 8]);
        }
        __syncthreads();                       // tiles ready (q_s too, first iter)
        // S^T = K.Q^T : D[y][x]; wave w owns x-strip [32w, 32w+32)
        f32x4 sacc[4][2] = {};
#pragma unroll
        for (int ks = 0; ks < 2; ++ks) {
            bf16x8 bq[2];
#pragma unroll
            for (int nt = 0; nt < 2; ++nt)
                bq[nt] = *(const bf16x8*)&q_s[(32 * w + nt * 16 + lm) * 64 + ks * 32 + lq * 8];
#pragma unroll
            for (int mt = 0; mt < 4; ++mt) {
                bf16x8 ak = *(const bf16x8*)&k_s[(mt * 16 + lm) * 64 + ks * 32 + lq * 8];
#pragma unroll
                for (int nt = 0; nt < 2; ++nt)
                    sacc[mt][nt] = MFMA16(ak, bq[nt], sacc[mt][nt]);
            }
        }
        // s = (qk + pq) * scale -> bf16 -> s_s (wave-private strip)
#pragma unroll
        for (int nt = 0; nt < 2; ++nt) {
            int xl = 32 * w + nt * 16 + lm;
            const unsigned int* pqc = (const unsigned int*)&pq4[nt];
#pragma unroll
            for (int mt = 0; mt < 4; ++mt) {
                unsigned int pw = pqc[mt];
                ushort4 o;
                o.x = f2bf((sacc[mt][nt][0] + __builtin_amdgcn_cvt_f32_fp8(pw, 0)) * 0.125f);
                o.y = f2bf((sacc[mt][nt][1] + __builtin_amdgcn_cvt_f32_fp8(pw, 1)) * 0.125f);
                o.z = f2bf((sacc[mt][nt][2] + __builtin_amdgcn_cvt_f32_fp8(pw, 2)) * 0.125f);
                o.w = f2bf((sacc[mt][nt][3] + __builtin_amdgcn_cvt_f32_fp8(pw, 3)) * 0.125f);
                *(ushort4*)&s_s[xl * 80 + mt * 16 + lq * 4] = o;
            }
        }
        // O += S.V  (A = s_s own strip, B = v_s)
#pragma unroll
        for (int ks = 0; ks < 2; ++ks) {
            bf16x8 as[2];
#pragma unroll
            for (int mt = 0; mt < 2; ++mt)
                as[mt] = *(const bf16x8*)&s_s[(32 * w + mt * 16 + lm) * 80 + ks * 32 + lq * 8];
#pragma unroll
            for (int nt = 0; nt < 4; ++nt) {
                bf16x8 bv = *(const bf16x8*)&v_s[(nt * 16 + lm) * 64 + ks * 32 + lq * 8];
#pragma unroll
                for (int mt = 0; mt < 2; ++mt)
                    oacc[mt][nt] = MFMA16(as[mt], bv, oacc[mt][nt]);
            }
        }
    }
    // write attn (B, S, E=h*64+d) bf16
    const int b = bh >> 4, h = bh & 15;
    for (int mt = 0; mt < 2; ++mt) {
        for (int nt = 0; nt < 4; ++nt) {
            int d = nt * 16 + lm;
            for (int i = 0; i < 4; ++i) {
                int s = x0 + 32 * w + mt * 16 + lq * 4 + i;
                attnb[((size_t)(b * 1024 + s)) * 1024 + h * 64 + d] = f2bf(oacc[mt][nt][i]);
            }
        }
    }
}

// --------------------------------------------------------------------------
// Out projection (m97-style): out(4096x1024 fp32) = attn(bf16)@WoutT^T + b
// grid (8,32), block 256
// --------------------------------------------------------------------------
__global__ __launch_bounds__(256, 2) void kgemm_out(const u16* __restrict__ A,
                                                    const u16* __restrict__ WT,
                                                    const float* __restrict__ bias,
                                                    float* __restrict__ out) {
    __shared__ u16 a_s[128 * 64];
    __shared__ u16 b_s[128 * 64];
    const int t = threadIdx.x;
    const int m0 = blockIdx.y * 128, n0 = blockIdx.x * 128;
    const int lane = t & 63, w = t >> 6, lm = lane & 15, lq = lane >> 4;
    const int mb = (w >> 1) * 64, nb = (w & 1) * 64;
    const int sr = t >> 3, sc = (t & 7) * 8;

    f32x4 acc[4][4] = {};
    for (int k0 = 0; k0 < 1024; k0 += 64) {
        __syncthreads();
#pragma unroll
        for (int p = 0; p < 4; ++p) {
            GLOAD16(&A [(size_t)(m0 + p * 32 + sr) * 1024 + k0 + sc], &a_s[p * 2048 + t * 8]);
            GLOAD16(&WT[(size_t)(n0 + p * 32 + sr) * 1024 + k0 + sc], &b_s[p * 2048 + t * 8]);
        }
        __syncthreads();
#pragma unroll
        for (int ks = 0; ks < 2; ++ks) {
            bf16x8 af[4], bfr[4];
#pragma unroll
            for (int mt = 0; mt < 4; ++mt)
                af[mt] = *(const bf16x8*)&a_s[(mb + mt * 16 + lm) * 64 + ks * 32 + lq * 8];
#pragma unroll
            for (int nt = 0; nt < 4; ++nt)
                bfr[nt] = *(const bf16x8*)&b_s[(nb + nt * 16 + lm) * 64 + ks * 32 + lq * 8];
#pragma unroll
            for (int mt = 0; mt < 4; ++mt)
#pragma unroll
                for (int nt = 0; nt < 4; ++nt)
                    acc[mt][nt] = MFMA16(af[mt], bfr[nt], acc[mt][nt]);
        }
    }
    for (int nt = 0; nt < 4; ++nt) {
        int col = n0 + nb + nt * 16 + lm;
        float bv = bias[col];
        for (int mt = 0; mt < 4; ++mt) {
            for (int i = 0; i < 4; ++i) {
                int row = m0 + mb + mt * 16 + lq * 4 + i;
                out[(size_t)row * 1024 + col] = acc[mt][nt][i] + bv;
            }
        }
    }
}

// --------------------------------------------------------------------------
extern "C" void kernel_launch(void* const* d_in, const int* in_sizes, int n_in,
                              void* d_out, int out_size, void* d_ws, size_t ws_size,
                              hipStream_t stream) {
    (void)in_sizes; (void)n_in; (void)out_size; (void)ws_size;
    const float* x    = (const float*)d_in[0];
    const float* Wqkv = (const float*)d_in[1];
    const float* bqkv = (const float*)d_in[2];
    const float* pe   = (const float*)d_in[3];
    const float* Wout = (const float*)d_in[4];
    const float* bout = (const float*)d_in[5];
    float* out = (float*)d_out;

    char* ws = (char*)d_ws;
    u16* xb    = (u16*)ws;  ws += (size_t)4096 * 1024 * 2;     // 8 MB
    u16* wqkvT = (u16*)ws;  ws += (size_t)3072 * 1024 * 2;     // 6 MB
    u16* woutT = (u16*)ws;  ws += (size_t)1024 * 1024 * 2;     // 2 MB
    u16* qb    = (u16*)ws;  ws += (size_t)64 * 1024 * 64 * 2;  // 8 MB
    u16* kb    = (u16*)ws;  ws += (size_t)64 * 1024 * 64 * 2;  // 8 MB
    u16* vtb   = (u16*)ws;  ws += (size_t)64 * 64 * 1024 * 2;  // 8 MB
    u16* attnb = (u16*)ws;  ws += (size_t)4 * 1024 * 1024 * 2; // 8 MB
    u8*  pq    = (u8*)ws;   ws += (size_t)64 * 1024 * 1024;    // 64 MB (fp8)

    kprep<<<3072, 256, 0, stream>>>(x, xb, Wqkv, wqkvT, Wout, woutT);
    kgemm_qkv<<<dim3(24, 32), 256, 0, stream>>>(xb, wqkvT, bqkv, qb, kb, vtb);
    kpq<<<1024, 256, 0, stream>>>(qb, pe, pq);
    kattn<<<512, 256, 0, stream>>>(qb, kb, vtb, pq, attnb);
    kgemm_out<<<dim3(8, 32), 256, 0, stream>>>(attnb, woutT, bout, out);
}